// Round 4
// baseline (218.618 us; speedup 1.0000x reference)
//
#include <hip/hip_runtime.h>
#include <math.h>

// GraphLaplacian: out[b,v] = || sum_w L[v,w] * verts[b,w,:] ||_2
// L is 6000x6000 fp32, ~13 nnz/row -> scan-bound (144 MB mandatory read).
// 4 contiguous rows per block, software-pipelined: loads for row r+1 are
// issued at the START of row r's phase-2 window so the vmcnt(0) drain at
// the following __syncthreads happens after gather latency covered it.
// launch_bounds(256,4): 128-VGPR cap -> no spill of the 2x6 float4 buffers.

#define NUM_V   6000
#define BATCH   32
#define ROW_F4  1500            // float4 per row
#define ROWS_PB 4
#define NBLOCKS (NUM_V / ROWS_PB)   // 1500
#define MAX_NNZ 256             // max row degree ~35; big margin

__device__ __forceinline__ void collect4(float4 a, int c0,
                                         int* cols, float* vals, int* cnt) {
    if ((a.x != 0.f) | (a.y != 0.f) | (a.z != 0.f) | (a.w != 0.f)) {
        if (a.x != 0.f) { int p = atomicAdd(cnt, 1); cols[p] = c0;     vals[p] = a.x; }
        if (a.y != 0.f) { int p = atomicAdd(cnt, 1); cols[p] = c0 + 1; vals[p] = a.y; }
        if (a.z != 0.f) { int p = atomicAdd(cnt, 1); cols[p] = c0 + 2; vals[p] = a.z; }
        if (a.w != 0.f) { int p = atomicAdd(cnt, 1); cols[p] = c0 + 3; vals[p] = a.w; }
    }
}

__device__ __forceinline__ void load_row(float4 (&R)[6], const float* L,
                                         int row, int t) {
    const float4* rp = reinterpret_cast<const float4*>(L) + (size_t)row * ROW_F4;
    R[0] = rp[t];
    R[1] = rp[t + 256];
    R[2] = rp[t + 512];
    R[3] = rp[t + 768];
    R[4] = rp[t + 1024];
    R[5] = (t < ROW_F4 - 1280) ? rp[t + 1280] : make_float4(0.f, 0.f, 0.f, 0.f);
}

__device__ __forceinline__ void collect6(const float4 (&R)[6], int t,
                                         int* cols, float* vals, int* cnt) {
    collect4(R[0], 4 * t,            cols, vals, cnt);
    collect4(R[1], 4 * (t + 256),    cols, vals, cnt);
    collect4(R[2], 4 * (t + 512),    cols, vals, cnt);
    collect4(R[3], 4 * (t + 768),    cols, vals, cnt);
    collect4(R[4], 4 * (t + 1024),   cols, vals, cnt);
    collect4(R[5], 4 * (t + 1280),   cols, vals, cnt);   // zero-filled tail -> no-op
}

__global__ __launch_bounds__(256, 4)
void graph_laplacian_kernel(const float* __restrict__ verts,
                            const float* __restrict__ L,
                            float* __restrict__ out) {
    __shared__ int   s_cols[2][MAX_NNZ];
    __shared__ float s_vals[2][MAX_NNZ];
    __shared__ int   s_cnt[2];
    __shared__ float s_part[192];

    const int t    = threadIdx.x;
    const int row0 = blockIdx.x * ROWS_PB;

    // phase-2 mapping: 192 threads = 2 per (batch,dim) pair (computed once)
    const int pr = t >> 1;            // pair 0..95
    const int hh = t & 1;             // half 0/1
    const int bb = pr / 3;
    const int dd = pr - 3 * bb;
    const float* vb = verts + (size_t)bb * (NUM_V * 3) + dd;

    float4 R[2][6];

    load_row(R[0], L, row0, t);
    if (t == 0) { s_cnt[0] = 0; s_cnt[1] = 0; }
    __syncthreads();                          // cnt init visible; drains row0 loads

    collect6(R[0], t, s_cols[0], s_vals[0], &s_cnt[0]);
    __syncthreads();                          // C0

    #pragma unroll
    for (int r = 0; r < ROWS_PB; ++r) {
        const int idx = r & 1;
        const int c   = min(s_cnt[idx], MAX_NNZ);

        // issue next row's loads NOW: latency hides under phase 2
        if (r + 1 < ROWS_PB)
            load_row(R[idx ^ 1], L, row0 + r + 1, t);
        if (t == 0) s_cnt[idx ^ 1] = 0;       // barrier-separated from its users

        // ---- phase 2: nnz gather, 4 independent loads in flight ----
        if (t < 192) {
            float acc = 0.f;
            for (int i = hh; i < c; i += 8) {
                const int  i1 = i + 2, i2 = i + 4, i3 = i + 6;
                const bool v1 = i1 < c, v2 = i2 < c, v3 = i3 < c;
                const int  c0 = s_cols[idx][i];
                const int  c1 = v1 ? s_cols[idx][i1] : 0;
                const int  c2 = v2 ? s_cols[idx][i2] : 0;
                const int  c3 = v3 ? s_cols[idx][i3] : 0;
                const float w0 = s_vals[idx][i];
                const float w1 = v1 ? s_vals[idx][i1] : 0.f;
                const float w2 = v2 ? s_vals[idx][i2] : 0.f;
                const float w3 = v3 ? s_vals[idx][i3] : 0.f;
                const float x0 = vb[(size_t)c0 * 3];
                const float x1 = vb[(size_t)c1 * 3];
                const float x2 = vb[(size_t)c2 * 3];
                const float x3 = vb[(size_t)c3 * 3];
                acc = fmaf(w0, x0, acc);
                acc = fmaf(w1, x1, acc);
                acc = fmaf(w2, x2, acc);
                acc = fmaf(w3, x3, acc);
            }
            s_part[t] = acc;
        }
        __syncthreads();                      // P_r (drains row r+1 loads, arrived)

        // ---- phase 3: combine halves + dims, write norm ----
        if (t < BATCH) {
            const float x = s_part[6 * t + 0] + s_part[6 * t + 1];
            const float y = s_part[6 * t + 2] + s_part[6 * t + 3];
            const float z = s_part[6 * t + 4] + s_part[6 * t + 5];
            out[(size_t)t * NUM_V + (row0 + r)] = sqrtf(fmaf(x, x, fmaf(y, y, z * z)));
        }

        if (r + 1 < ROWS_PB) {
            collect6(R[idx ^ 1], t, s_cols[idx ^ 1], s_vals[idx ^ 1], &s_cnt[idx ^ 1]);
            __syncthreads();                  // C_{r+1}
        }
    }
}

extern "C" void kernel_launch(void* const* d_in, const int* in_sizes, int n_in,
                              void* d_out, int out_size, void* d_ws, size_t ws_size,
                              hipStream_t stream) {
    const float* verts = (const float*)d_in[0];   // (32, 6000, 3) fp32
    const float* L     = (const float*)d_in[1];   // (6000, 6000) fp32
    float* out         = (float*)d_out;           // (32, 6000)  fp32

    graph_laplacian_kernel<<<NBLOCKS, 256, 0, stream>>>(verts, L, out);
}